// Round 8
// baseline (110.524 us; speedup 1.0000x reference)
//
#include <hip/hip_runtime.h>

#define NS 65536
#define DD 32
#define RR 128
#define SPB 16            // samples per block
#define STR 132           // padded LDS row stride (floats)

// Pre-pass: fold clamp/log2/negate into params, repack float4-interleaved by
// d-chunk: P*[c][r] = float4 of dims 4c..4c+3 for rule r.
__global__ void anfis_pre(const float* __restrict__ A, const float* __restrict__ B,
                          const float* __restrict__ C, float4* __restrict__ PW,
                          float4* __restrict__ PN, float4* __restrict__ PK,
                          float* __restrict__ BIAS) {
    int i = blockIdx.x * 256 + threadIdx.x;     // i = r*8 + c
    if (i < RR * 8) {
        int r = i >> 3, c = i & 7;
        float4 va = *(const float4*)(A + r * DD + c * 4);
        float4 vb = *(const float4*)(B + r * DD + c * 4);
        float w0 = 0.8493218003f / fmaxf(vb.x, 1e-8f);   // sqrt(log2e/2)/clamp(b)
        float w1 = 0.8493218003f / fmaxf(vb.y, 1e-8f);
        float w2 = 0.8493218003f / fmaxf(vb.z, 1e-8f);
        float w3 = 0.8493218003f / fmaxf(vb.w, 1e-8f);
        int o = c * RR + r;
        PW[o] = make_float4(w0, w1, w2, w3);
        PN[o] = make_float4(-va.x * w0, -va.y * w1, -va.z * w2, -va.w * w3);
        PK[o] = make_float4(C[r*(DD+1)+4*c+0], C[r*(DD+1)+4*c+1],
                            C[r*(DD+1)+4*c+2], C[r*(DD+1)+4*c+3]);
        if (c == 0) BIAS[r] = C[r * (DD + 1) + DD];
    }
}

__device__ __forceinline__ float rdlane(float v, int ln) {
    return __int_as_float(__builtin_amdgcn_readlane(__float_as_int(v), ln));
}

// Block = 128 threads = 2 waves; thread == rule; 16 samples/block. X tile (2 KB)
// loaded ONCE per wave via 2 coalesced global_load_dwordx4 into registers; in the
// hot loop x comes from v_readlane (VALU, zero memory) as the single SGPR operand
// of each FMA (3-op form preserved). This removes the streaming-X latency that
// capped R4/R6/R7 at VALUBusy ~25-33% (cold s_loads + lgkmcnt(0) coarse drains).
__global__ __launch_bounds__(128, 4) void anfis_main(
    const float* __restrict__ X,
    const float4* __restrict__ PW, const float4* __restrict__ PN,
    const float4* __restrict__ PK, const float* __restrict__ BIAS,
    float* __restrict__ out_pred, float* __restrict__ out_str,
    float* __restrict__ out_norm)
{
    __shared__ float SBUF[SPB * STR];
    __shared__ float PBUF[SPB * STR];
    __shared__ float pS[SPB][8];
    __shared__ float pD[SPB][8];
    __shared__ float scale_lds[SPB];

    const int tid   = threadIdx.x;        // rule id
    const int lane  = tid & 63;
    const int nbase = blockIdx.x * SPB;

    // ---- X tile -> registers: float4 #f covers sample f/8, dims 4*(f%8).. ----
    const float4* Xf4 = (const float4*)(X + (size_t)nbase * DD);
    float4 q0 = Xf4[lane];        // float4s 0..63   (samples 0..7)
    float4 q1 = Xf4[64 + lane];   // float4s 64..127 (samples 8..15)

    float as_[SPB], ar_[SPB];
    const float bias = BIAS[tid];
    #pragma unroll
    for (int s = 0; s < SPB; ++s) { as_[s] = 0.0f; ar_[s] = bias; }

    float4 w4 = PW[tid], n4 = PN[tid], k4 = PK[tid];   // chunk 0 params
    #pragma unroll 1
    for (int c = 0; c < 8; ++c) {
        const int cn = ((c + 1) & 7) * RR + tid;       // prefetch next chunk
        float4 wn = PW[cn], nn = PN[cn], kn = PK[cn];
        #pragma unroll
        for (int s = 0; s < SPB; ++s) {
            const int ln = ((s & 7) << 3) + c;         // lane of float4 (s,c)
            float x0, x1, x2, x3;
            if (s < 8) { x0 = rdlane(q0.x, ln); x1 = rdlane(q0.y, ln);
                         x2 = rdlane(q0.z, ln); x3 = rdlane(q0.w, ln); }
            else       { x0 = rdlane(q1.x, ln); x1 = rdlane(q1.y, ln);
                         x2 = rdlane(q1.z, ln); x3 = rdlane(q1.w, ln); }
            float t0 = fmaf(x0, w4.x, n4.x); as_[s] = fmaf(t0, t0, as_[s]); ar_[s] = fmaf(x0, k4.x, ar_[s]);
            float t1 = fmaf(x1, w4.y, n4.y); as_[s] = fmaf(t1, t1, as_[s]); ar_[s] = fmaf(x1, k4.y, ar_[s]);
            float t2 = fmaf(x2, w4.z, n4.z); as_[s] = fmaf(t2, t2, as_[s]); ar_[s] = fmaf(x2, k4.z, ar_[s]);
            float t3 = fmaf(x3, w4.w, n4.w); as_[s] = fmaf(t3, t3, as_[s]); ar_[s] = fmaf(x3, k4.w, ar_[s]);
        }
        w4 = wn; n4 = nn; k4 = kn;
    }

    #pragma unroll
    for (int s = 0; s < SPB; ++s) {
        float st = __builtin_amdgcn_exp2f(-as_[s]);
        SBUF[s * STR + tid] = st;
        PBUF[s * STR + tid] = st * ar_[s];
    }
    __syncthreads();

    // ---- per-sample sums over rules: 128 threads = 16 samples x 8 octants ----
    {
        int s = tid >> 3, o = tid & 7;
        const float4* srow = (const float4*)&SBUF[s * STR + o * 16];
        const float4* prow = (const float4*)&PBUF[s * STR + o * 16];
        float ss = 0.f, dd = 0.f;
        #pragma unroll
        for (int k = 0; k < 4; ++k) {
            float4 v = srow[k]; ss += (v.x + v.y) + (v.z + v.w);
            float4 p = prow[k]; dd += (p.x + p.y) + (p.z + p.w);
        }
        pS[s][o] = ss; pD[s][o] = dd;
    }
    __syncthreads();
    if (tid < SPB) {
        float ss = 0.f, dd = 0.f;
        #pragma unroll
        for (int o = 0; o < 8; ++o) { ss += pS[tid][o]; dd += pD[tid][o]; }
        float sc = 1.0f / (ss + 1e-8f);
        out_pred[nbase + tid] = dd * sc;
        scale_lds[tid] = sc;
    }
    __syncthreads();

    // ---- flush strengths + normalized, float4-coalesced ----
    #pragma unroll
    for (int it = 0; it < 4; ++it) {
        int f   = it * 128 + tid;
        int row = f >> 5;
        int col = f & 31;
        float4 v = *(const float4*)&SBUF[row * STR + col * 4];
        float sc = scale_lds[row];
        size_t base = ((size_t)(nbase + row)) * RR + col * 4;
        *(float4*)(out_str  + base) = v;
        *(float4*)(out_norm + base) = make_float4(v.x * sc, v.y * sc, v.z * sc, v.w * sc);
    }
}

extern "C" void kernel_launch(void* const* d_in, const int* in_sizes, int n_in,
                              void* d_out, int out_size, void* d_ws, size_t ws_size,
                              hipStream_t stream) {
    const float* X = (const float*)d_in[0];
    const float* A = (const float*)d_in[1];
    const float* B = (const float*)d_in[2];
    const float* C = (const float*)d_in[3];

    float* wsf  = (float*)d_ws;
    float4* PW  = (float4*)(wsf);                 // 4096 floats
    float4* PN  = (float4*)(wsf + RR * DD);       // 4096 floats
    float4* PK  = (float4*)(wsf + 2 * RR * DD);   // 4096 floats
    float* BIAS = wsf + 3 * RR * DD;              // 128 floats

    float* pred = (float*)d_out;
    float* str  = pred + NS;
    float* nrm  = str + (size_t)NS * RR;

    anfis_pre<<<dim3(4), dim3(256), 0, stream>>>(A, B, C, PW, PN, PK, BIAS);
    anfis_main<<<dim3(NS / SPB), dim3(128), 0, stream>>>(X, PW, PN, PK, BIAS, pred, str, nrm);
}

// Round 9
// 106.077 us; speedup vs baseline: 1.0419x; 1.0419x over previous
//
#include <hip/hip_runtime.h>

#define NS 65536
#define DD 32
#define RR 128
#define SPB 16            // samples per block
#define STR 132           // padded LDS row stride (floats)

// R4 structure + per-wave L2 warming of the X tile.
// Block = 128 threads = 2 waves; thread == rule. Block covers 16 samples, indexed
// only by blockIdx => X-row loads are uniform -> SGPRs (double-buffered s_loads).
// NEW: each wave issues one coalesced global_load_dwordx4 covering its half of the
// X tile (wave0 rows 0-7, wave1 rows 8-15) at kernel start, asm-sunk. This pulls
// all 16 lines into L2 (~900cyc, once, overlapped with param loads) so the s_load
// loop runs L2-hot (~300cyc) and distance-1 prefetch covers it. R4's measured
// VALUBusy(31%)*cycles == static VALU count => the other 70% was cold-X wait.
__global__ __launch_bounds__(128, 4) void anfis_main(
    const float* __restrict__ X, const float* __restrict__ A,
    const float* __restrict__ B, const float* __restrict__ C,
    float* __restrict__ out_pred, float* __restrict__ out_str,
    float* __restrict__ out_norm)
{
    __shared__ float SBUF[SPB * STR];   // strengths, row = sample-in-block
    __shared__ float PBUF[SPB * STR];   // strength * rule_out
    __shared__ float pS[SPB][8];
    __shared__ float pD[SPB][8];
    __shared__ float scale_lds[SPB];

    const int tid   = threadIdx.x;      // rule id
    const int w     = tid >> 6;         // wave id (0,1)
    const int lane  = tid & 63;
    const int nbase = blockIdx.x * SPB;

    // ---- L2 warming: wave w loads rows w*8..w*8+7 (1 KB) in one dwordx4/lane ----
    {
        const float4* Xf4 = (const float4*)(X + (size_t)(nbase + w * 8) * DD);
        float4 q = Xf4[lane];           // 64 lanes x 16 B = 8 rows x 128 B
        asm volatile("" :: "v"(q.x), "v"(q.y), "v"(q.z), "v"(q.w));
    }

    // ---- per-thread rule params -> VGPRs ----
    float w_[DD], naw_[DD], ck_[DD], bias;
    {
        const float4* av = (const float4*)(A + tid * DD);
        const float4* bv = (const float4*)(B + tid * DD);
        #pragma unroll
        for (int i = 0; i < 8; ++i) {
            float4 va = av[i], vb = bv[i];
            float w0 = 0.8493218003f * __builtin_amdgcn_rcpf(fmaxf(vb.x, 1e-8f));
            float w1 = 0.8493218003f * __builtin_amdgcn_rcpf(fmaxf(vb.y, 1e-8f));
            float w2 = 0.8493218003f * __builtin_amdgcn_rcpf(fmaxf(vb.z, 1e-8f));
            float w3 = 0.8493218003f * __builtin_amdgcn_rcpf(fmaxf(vb.w, 1e-8f));
            w_[4*i+0] = w0; naw_[4*i+0] = -va.x * w0;
            w_[4*i+1] = w1; naw_[4*i+1] = -va.y * w1;
            w_[4*i+2] = w2; naw_[4*i+2] = -va.z * w2;
            w_[4*i+3] = w3; naw_[4*i+3] = -va.w * w3;
        }
        #pragma unroll
        for (int d = 0; d < DD; ++d) ck_[d] = C[tid * (DD + 1) + d];
        bias = C[tid * (DD + 1) + DD];
    }

    const float* Xg = X + (size_t)nbase * DD;   // uniform base (blockIdx only)

    float xa[DD], xb[DD];   // uniform values -> SGPRs
#define LOADX(arr, jj) { _Pragma("unroll") \
    for (int i = 0; i < DD; ++i) arr[i] = Xg[(jj) * DD + i]; }

#define COMPUTE(arr, jj) { \
    float s0 = 0.f, s1 = 0.f, s2 = 0.f, s3 = 0.f; \
    float r0 = bias, r1 = 0.f, r2 = 0.f, r3 = 0.f; \
    _Pragma("unroll") \
    for (int d = 0; d < DD; d += 4) { \
        float t0 = fmaf(arr[d+0], w_[d+0], naw_[d+0]); s0 = fmaf(t0, t0, s0); r0 = fmaf(arr[d+0], ck_[d+0], r0); \
        float t1 = fmaf(arr[d+1], w_[d+1], naw_[d+1]); s1 = fmaf(t1, t1, s1); r1 = fmaf(arr[d+1], ck_[d+1], r1); \
        float t2 = fmaf(arr[d+2], w_[d+2], naw_[d+2]); s2 = fmaf(t2, t2, s2); r2 = fmaf(arr[d+2], ck_[d+2], r2); \
        float t3 = fmaf(arr[d+3], w_[d+3], naw_[d+3]); s3 = fmaf(t3, t3, s3); r3 = fmaf(arr[d+3], ck_[d+3], r3); \
    } \
    float st = __builtin_amdgcn_exp2f(-((s0 + s1) + (s2 + s3))); \
    float ro = (r0 + r1) + (r2 + r3); \
    SBUF[(jj) * STR + tid] = st; \
    PBUF[(jj) * STR + tid] = st * ro; }

    LOADX(xa, 0)
    for (int j = 0; j < SPB; j += 2) {
        LOADX(xb, j + 1)                    // prefetch j+1 while computing j
        COMPUTE(xa, j)
        if (j + 2 < SPB) LOADX(xa, j + 2)   // prefetch j+2 while computing j+1
        COMPUTE(xb, j + 1)
    }
#undef LOADX
#undef COMPUTE
    __syncthreads();

    // ---- per-sample sums over rules: 128 threads = 16 samples x 8 octants ----
    {
        int s = tid >> 3, o = tid & 7;      // 16B-group o covers 16 floats
        const float4* srow = (const float4*)&SBUF[s * STR + o * 16];
        const float4* prow = (const float4*)&PBUF[s * STR + o * 16];
        float ss = 0.f, dd = 0.f;
        #pragma unroll
        for (int k = 0; k < 4; ++k) {
            float4 v = srow[k]; ss += (v.x + v.y) + (v.z + v.w);
            float4 p = prow[k]; dd += (p.x + p.y) + (p.z + p.w);
        }
        pS[s][o] = ss; pD[s][o] = dd;
    }
    __syncthreads();
    if (tid < SPB) {
        float ss = 0.f, dd = 0.f;
        #pragma unroll
        for (int o = 0; o < 8; ++o) { ss += pS[tid][o]; dd += pD[tid][o]; }
        float sc = 1.0f / (ss + 1e-8f);
        out_pred[nbase + tid] = dd * sc;
        scale_lds[tid] = sc;
    }
    __syncthreads();

    // ---- flush strengths + normalized, float4-coalesced (1 KB contiguous per wave) ----
    #pragma unroll
    for (int it = 0; it < 4; ++it) {
        int f   = it * 128 + tid;       // float4 index over 16x32 tile
        int row = f >> 5;
        int col = f & 31;
        float4 v = *(const float4*)&SBUF[row * STR + col * 4];
        float sc = scale_lds[row];
        size_t base = ((size_t)(nbase + row)) * RR + col * 4;
        *(float4*)(out_str  + base) = v;
        *(float4*)(out_norm + base) = make_float4(v.x * sc, v.y * sc, v.z * sc, v.w * sc);
    }
}

extern "C" void kernel_launch(void* const* d_in, const int* in_sizes, int n_in,
                              void* d_out, int out_size, void* d_ws, size_t ws_size,
                              hipStream_t stream) {
    const float* X = (const float*)d_in[0];
    const float* A = (const float*)d_in[1];
    const float* B = (const float*)d_in[2];
    const float* C = (const float*)d_in[3];

    float* pred = (float*)d_out;
    float* str  = pred + NS;
    float* nrm  = str + (size_t)NS * RR;

    anfis_main<<<dim3(NS / SPB), dim3(128), 0, stream>>>(X, A, B, C, pred, str, nrm);
}